// Round 1
// baseline (2074.817 us; speedup 1.0000x reference)
//
#include <hip/hip_runtime.h>
#include <hip/hip_bf16.h>
#include <math.h>

#define HF 96

// ---------------- kernel 0: tp = time_feats @ W_tp + b_tp ----------------
__global__ void k_tp(const float* __restrict__ timef,
                     const float* __restrict__ W,
                     const float* __restrict__ b,
                     float* __restrict__ tp) {
    int j = threadIdx.x;
    if (j < HF) {
        float acc = b[j];
#pragma unroll 8
        for (int k = 0; k < HF; ++k) acc = fmaf(timef[k], W[k * HF + j], acc);
        tp[j] = acc;
    }
}

// ------------- kernel 1: fused node GEMMs (4 matrices) -------------------
// block (96, 2): each row of 96 threads handles one node.
__global__ void k_node_gemm(const float* __restrict__ nf,
                            const float* __restrict__ Wsg, const float* __restrict__ bsg,
                            const float* __restrict__ Wdg, const float* __restrict__ bdg,
                            const float* __restrict__ Wdu, const float* __restrict__ bdu,
                            const float* __restrict__ Wsu, const float* __restrict__ bsu,
                            const float* __restrict__ tp,
                            float* __restrict__ esrc, float* __restrict__ edstA,
                            float* __restrict__ Bh, float* __restrict__ xlin,
                            int n) {
    int j = threadIdx.x;                       // 0..95 (output feature)
    int ty = threadIdx.y;                      // 0..1
    int node = blockIdx.x * 2 + ty;
    bool valid = (node < n);

    __shared__ float row[2][HF];
    row[ty][j] = valid ? nf[(size_t)node * HF + j] : 0.0f;
    __syncthreads();

    const float* r = row[ty];
    float a0 = bsg[j] + tp[j];
    float a1 = bdg[j];
    float a2 = bdu[j];
    float a3 = bsu[j];
#pragma unroll 4
    for (int k = 0; k < HF; ++k) {
        float v = r[k];
        a0 = fmaf(v, Wsg[k * HF + j], a0);
        a1 = fmaf(v, Wdg[k * HF + j], a1);
        a2 = fmaf(v, Wdu[k * HF + j], a2);
        a3 = fmaf(v, Wsu[k * HF + j], a3);
    }
    if (valid) {
        size_t o = (size_t)node * HF + j;
        esrc[o] = a0;
        edstA[o] = a1;
        Bh[o] = a2;
        xlin[o] = a3;
    }
}

// ------------- kernel 2: edge gate GEMM + sigmoid + scatter + LN/SiLU ----
// block (96, 4): each row of 96 threads handles one edge.
__global__ void k_edge(const float* __restrict__ ef,
                       const int* __restrict__ src, const int* __restrict__ dst,
                       const float* __restrict__ Weg, const float* __restrict__ beg,
                       const float* __restrict__ esrc, const float* __restrict__ edstA,
                       const float* __restrict__ Bh,
                       const float* __restrict__ g_ln, const float* __restrict__ b_ln,
                       float* __restrict__ ssh, float* __restrict__ ss,
                       float* __restrict__ y, int e_total) {
    int j = threadIdx.x;   // 0..95
    int ty = threadIdx.y;  // 0..3
    int e = blockIdx.x * 4 + ty;
    bool valid = (e < e_total);

    __shared__ float erow[4][HF];
    __shared__ float reds[4][HF];
    __shared__ float redq[4][HF];

    float efv = valid ? ef[(size_t)e * HF + j] : 0.0f;
    erow[ty][j] = efv;
    __syncthreads();

    float gate = beg[j];
#pragma unroll 8
    for (int k = 0; k < HF; ++k) gate = fmaf(erow[ty][k], Weg[k * HF + j], gate);

    float mm = 0.0f;
    if (valid) {
        int s = src[e];
        int d = dst[e];
        mm = esrc[(size_t)s * HF + j] + edstA[(size_t)d * HF + j] + gate;
        float sg = 1.0f / (1.0f + __expf(-mm));
        atomicAdd(&ss[(size_t)d * HF + j], sg);
        atomicAdd(&ssh[(size_t)d * HF + j], sg * Bh[(size_t)s * HF + j]);
    }

    // LayerNorm over the 96 features of m (sum and sum of squares)
    reds[ty][j] = mm;
    redq[ty][j] = mm * mm;
    __syncthreads();
    if (j < 48) { reds[ty][j] += reds[ty][j + 48]; redq[ty][j] += redq[ty][j + 48]; } __syncthreads();
    if (j < 24) { reds[ty][j] += reds[ty][j + 24]; redq[ty][j] += redq[ty][j + 24]; } __syncthreads();
    if (j < 12) { reds[ty][j] += reds[ty][j + 12]; redq[ty][j] += redq[ty][j + 12]; } __syncthreads();
    if (j < 6)  { reds[ty][j] += reds[ty][j + 6];  redq[ty][j] += redq[ty][j + 6];  } __syncthreads();
    if (j < 3)  { reds[ty][j] += reds[ty][j + 3];  redq[ty][j] += redq[ty][j + 3];  } __syncthreads();

    if (valid) {
        float sum = reds[ty][0] + reds[ty][1] + reds[ty][2];
        float sq  = redq[ty][0] + redq[ty][1] + redq[ty][2];
        float mean = sum * (1.0f / HF);
        float var  = sq * (1.0f / HF) - mean * mean;
        float lnv  = (mm - mean) * rsqrtf(var + 1e-5f) * g_ln[j] + b_ln[j];
        float silu = lnv / (1.0f + __expf(-lnv));
        y[(size_t)e * HF + j] = efv + silu;
    }
}

// ------------- kernel 3: node finalize: h, LN, SiLU, residual ------------
// block (96, 4): each row handles one node. x holds x_lin on entry.
__global__ void k_node_fin(const float* __restrict__ nf,
                           const float* __restrict__ ssh, const float* __restrict__ ss,
                           const float* __restrict__ g_ln, const float* __restrict__ b_ln,
                           float* __restrict__ x,
                           int n) {
    int j = threadIdx.x;
    int ty = threadIdx.y;
    int node = blockIdx.x * 4 + ty;
    bool valid = (node < n);

    float xv = 0.0f;
    if (valid) {
        size_t o = (size_t)node * HF + j;
        float h = ssh[o] / (ss[o] + 1e-6f);
        xv = x[o] + h;
    }

    __shared__ float reds[4][HF];
    __shared__ float redq[4][HF];
    reds[ty][j] = xv;
    redq[ty][j] = xv * xv;
    __syncthreads();
    if (j < 48) { reds[ty][j] += reds[ty][j + 48]; redq[ty][j] += redq[ty][j + 48]; } __syncthreads();
    if (j < 24) { reds[ty][j] += reds[ty][j + 24]; redq[ty][j] += redq[ty][j + 24]; } __syncthreads();
    if (j < 12) { reds[ty][j] += reds[ty][j + 12]; redq[ty][j] += redq[ty][j + 12]; } __syncthreads();
    if (j < 6)  { reds[ty][j] += reds[ty][j + 6];  redq[ty][j] += redq[ty][j + 6];  } __syncthreads();
    if (j < 3)  { reds[ty][j] += reds[ty][j + 3];  redq[ty][j] += redq[ty][j + 3];  } __syncthreads();

    if (valid) {
        float sum = reds[ty][0] + reds[ty][1] + reds[ty][2];
        float sq  = redq[ty][0] + redq[ty][1] + redq[ty][2];
        float mean = sum * (1.0f / HF);
        float var  = sq * (1.0f / HF) - mean * mean;
        float lnv  = (xv - mean) * rsqrtf(var + 1e-5f) * g_ln[j] + b_ln[j];
        float silu = lnv / (1.0f + __expf(-lnv));
        size_t o = (size_t)node * HF + j;
        x[o] = nf[o] + silu;
    }
}

extern "C" void kernel_launch(void* const* d_in, const int* in_sizes, int n_in,
                              void* d_out, int out_size, void* d_ws, size_t ws_size,
                              hipStream_t stream) {
    const float* node_feats = (const float*)d_in[0];
    const float* edge_feats = (const float*)d_in[1];
    const float* time_feats = (const float*)d_in[2];
    const int*   src        = (const int*)d_in[3];
    const int*   dst        = (const int*)d_in[4];
    const float* W_tp = (const float*)d_in[5];  const float* b_tp = (const float*)d_in[6];
    const float* W_sg = (const float*)d_in[7];  const float* b_sg = (const float*)d_in[8];
    const float* W_dg = (const float*)d_in[9];  const float* b_dg = (const float*)d_in[10];
    const float* W_eg = (const float*)d_in[11]; const float* b_eg = (const float*)d_in[12];
    const float* W_su = (const float*)d_in[13]; const float* b_su = (const float*)d_in[14];
    const float* W_du = (const float*)d_in[15]; const float* b_du = (const float*)d_in[16];
    const float* g_ln_e = (const float*)d_in[17]; const float* b_ln_e = (const float*)d_in[18];
    const float* g_ln_n = (const float*)d_in[19]; const float* b_ln_n = (const float*)d_in[20];

    int n = in_sizes[0] / HF;   // 100000
    int e = in_sizes[1] / HF;   // 800000

    // workspace layout (floats): tp[128] | esrc[n*H] | edst[n*H] | Bh[n*H] | ssh[n*H] | ss[n*H]
    float* ws    = (float*)d_ws;
    float* tp    = ws;
    float* esrc  = ws + 128;
    float* edstA = esrc  + (size_t)n * HF;
    float* Bh    = edstA + (size_t)n * HF;
    float* ssh   = Bh    + (size_t)n * HF;
    float* ss    = ssh   + (size_t)n * HF;

    float* x = (float*)d_out;             // [n, H]
    float* y = x + (size_t)n * HF;        // [e, H]

    // zero the scatter accumulators (graph-capture-safe)
    hipMemsetAsync(ssh, 0, 2 * (size_t)n * HF * sizeof(float), stream);

    k_tp<<<1, 128, 0, stream>>>(time_feats, W_tp, b_tp, tp);

    dim3 b1(HF, 2);
    k_node_gemm<<<(n + 1) / 2, b1, 0, stream>>>(node_feats,
                                                W_sg, b_sg, W_dg, b_dg,
                                                W_du, b_du, W_su, b_su,
                                                tp, esrc, edstA, Bh, x, n);

    dim3 b2(HF, 4);
    k_edge<<<(e + 3) / 4, b2, 0, stream>>>(edge_feats, src, dst, W_eg, b_eg,
                                           esrc, edstA, Bh, g_ln_e, b_ln_e,
                                           ssh, ss, y, e);

    k_node_fin<<<(n + 3) / 4, b2, 0, stream>>>(node_feats, ssh, ss,
                                               g_ln_n, b_ln_n, x, n);
}

// Round 4
// 1281.069 us; speedup vs baseline: 1.6196x; 1.6196x over previous
//
#include <hip/hip_runtime.h>
#include <hip/hip_bf16.h>
#include <math.h>

#define HF 96

typedef __attribute__((ext_vector_type(8))) short bf16x8;
typedef __attribute__((ext_vector_type(4))) float f32x4;

__device__ __forceinline__ short f2b(float x) {
    __hip_bfloat16 h = __float2bfloat16(x);
    return *reinterpret_cast<short*>(&h);
}
__device__ __forceinline__ float b2f(short s) {
    __hip_bfloat16 h = *reinterpret_cast<__hip_bfloat16*>(&s);
    return __bfloat162float(h);
}

// ---- prep: transpose 5 weight matrices to bf16 hi/lo [outfeat][k] -------
__global__ void k_prep(const float* __restrict__ Weg, const float* __restrict__ Wsg,
                       const float* __restrict__ Wdg, const float* __restrict__ Wdu,
                       const float* __restrict__ Wsu,
                       short* __restrict__ WegH, short* __restrict__ WegL,
                       short* __restrict__ WT4H, short* __restrict__ WT4L) {
    int c = threadIdx.x;   // out-feature
    int k = blockIdx.x;    // input k
    if (c >= HF) return;
    const float* Ws[5] = {Weg, Wsg, Wdg, Wdu, Wsu};
#pragma unroll
    for (int w = 0; w < 5; ++w) {
        float v = Ws[w][k * HF + c];
        short hi = f2b(v);
        short lo = f2b(v - b2f(hi));
        if (w == 0) { WegH[c * HF + k] = hi; WegL[c * HF + k] = lo; }
        else {
            WT4H[((w - 1) * HF + c) * HF + k] = hi;
            WT4L[((w - 1) * HF + c) * HF + k] = lo;
        }
    }
}

// ---- bias pack: bias4[0]=b_sg+tp, [1]=b_dg, [2]=b_du, [3]=b_su ----------
__global__ void k_bias(const float* __restrict__ timef, const float* __restrict__ Wtp,
                       const float* __restrict__ btp,
                       const float* __restrict__ bsg, const float* __restrict__ bdg,
                       const float* __restrict__ bdu, const float* __restrict__ bsu,
                       float* __restrict__ bias4) {
    int j = threadIdx.x;
    if (j >= HF) return;
    float acc = btp[j];
#pragma unroll 8
    for (int k = 0; k < HF; ++k) acc = fmaf(timef[k], Wtp[k * HF + j], acc);
    bias4[0 * HF + j] = bsg[j] + acc;
    bias4[1 * HF + j] = bdg[j];
    bias4[2 * HF + j] = bdu[j];
    bias4[3 * HF + j] = bsu[j];
}

// load a row's A-fragments (hi+lo) for 3 K-tiles
__device__ __forceinline__ void load_afrag(const float* __restrict__ ap,
                                           bf16x8* ah, bf16x8* al) {
#pragma unroll
    for (int kt = 0; kt < 3; ++kt) {
        float4 f0 = *(const float4*)(ap + kt * 32);
        float4 f1 = *(const float4*)(ap + kt * 32 + 4);
        float f[8] = {f0.x, f0.y, f0.z, f0.w, f1.x, f1.y, f1.z, f1.w};
        bf16x8 h, l;
#pragma unroll
        for (int t = 0; t < 8; ++t) {
            h[t] = f2b(f[t]);
            l[t] = f2b(f[t] - b2f(h[t]));
        }
        ah[kt] = h; al[kt] = l;
    }
}

// ---- node GEMMs via split-bf16 MFMA: esrc, edstA, Bh(bf16), xlin --------
__global__ __launch_bounds__(256)
void k_node_mfma(const float* __restrict__ nf,
                 const short* __restrict__ WT4H, const short* __restrict__ WT4L,
                 const float* __restrict__ bias4,
                 float* __restrict__ esrc, float* __restrict__ edstA,
                 short* __restrict__ bh16, float* __restrict__ xlin, int n) {
    int wid = threadIdx.x >> 6;
    int lane = threadIdx.x & 63;
    int lr = lane & 15, lg = lane >> 4;
    int nbase = blockIdx.x * 64 + wid * 16;

    bf16x8 ah[3], al[3];
    {
        int arow = nbase + lr; if (arow > n - 1) arow = n - 1;
        load_afrag(nf + (size_t)arow * HF + lg * 8, ah, al);
    }

#pragma unroll
    for (int w = 0; w < 4; ++w) {
#pragma unroll
        for (int tn = 0; tn < 6; ++tn) {
            f32x4 acc = {0.f, 0.f, 0.f, 0.f};
            int feat = tn * 16 + lr;
            size_t boff = (size_t)(w * HF + feat) * HF + lg * 8;
#pragma unroll
            for (int kt = 0; kt < 3; ++kt) {
                bf16x8 bh = *(const bf16x8*)(WT4H + boff + kt * 32);
                bf16x8 bl = *(const bf16x8*)(WT4L + boff + kt * 32);
                acc = __builtin_amdgcn_mfma_f32_16x16x32_bf16(ah[kt], bh, acc, 0, 0, 0);
                acc = __builtin_amdgcn_mfma_f32_16x16x32_bf16(ah[kt], bl, acc, 0, 0, 0);
                acc = __builtin_amdgcn_mfma_f32_16x16x32_bf16(al[kt], bh, acc, 0, 0, 0);
            }
            float bias = bias4[w * HF + feat];
#pragma unroll
            for (int r = 0; r < 4; ++r) {
                int node = nbase + lg * 4 + r;
                if (node < n) {
                    float v = acc[r] + bias;
                    size_t o = (size_t)node * HF + feat;
                    if (w == 0)      esrc[o]  = v;
                    else if (w == 1) edstA[o] = v;
                    else if (w == 2) bh16[o]  = f2b(v);
                    else             xlin[o]  = v;
                }
            }
        }
    }
}

// ---- edge: gate GEMM + gathers + sigmoid + atomics; stage raw m into y --
__global__ __launch_bounds__(256)
void k_edge_mfma(const float* __restrict__ ef, const int* __restrict__ src,
                 const int* __restrict__ dst,
                 const short* __restrict__ WegH, const short* __restrict__ WegL,
                 const float* __restrict__ beg,
                 const float* __restrict__ esrc, const float* __restrict__ edstA,
                 const short* __restrict__ bh16,
                 float* __restrict__ ssh, float* __restrict__ ss,
                 float* __restrict__ y, int E) {
    int wid = threadIdx.x >> 6;
    int lane = threadIdx.x & 63;
    int lr = lane & 15, lg = lane >> 4;
    int ebase = blockIdx.x * 64 + wid * 16;

    bf16x8 ah[3], al[3];
    {
        int arow = ebase + lr; if (arow > E - 1) arow = E - 1;
        load_afrag(ef + (size_t)arow * HF + lg * 8, ah, al);
    }

    f32x4 acc[6];
#pragma unroll
    for (int tn = 0; tn < 6; ++tn) {
        acc[tn] = (f32x4){0.f, 0.f, 0.f, 0.f};
        size_t boff = (size_t)(tn * 16 + lr) * HF + lg * 8;
#pragma unroll
        for (int kt = 0; kt < 3; ++kt) {
            bf16x8 bh = *(const bf16x8*)(WegH + boff + kt * 32);
            bf16x8 bl = *(const bf16x8*)(WegL + boff + kt * 32);
            acc[tn] = __builtin_amdgcn_mfma_f32_16x16x32_bf16(ah[kt], bh, acc[tn], 0, 0, 0);
            acc[tn] = __builtin_amdgcn_mfma_f32_16x16x32_bf16(ah[kt], bl, acc[tn], 0, 0, 0);
            acc[tn] = __builtin_amdgcn_mfma_f32_16x16x32_bf16(al[kt], bh, acc[tn], 0, 0, 0);
        }
    }

    int e_r[4], s_r[4], d_r[4];
    bool val[4];
#pragma unroll
    for (int r = 0; r < 4; ++r) {
        e_r[r] = ebase + lg * 4 + r;
        val[r] = (e_r[r] < E);
        int ec = val[r] ? e_r[r] : E - 1;
        s_r[r] = src[ec];
        d_r[r] = dst[ec];
    }

#pragma unroll
    for (int tn = 0; tn < 6; ++tn) {
        int feat = tn * 16 + lr;
        float bg = beg[feat];
#pragma unroll
        for (int r = 0; r < 4; ++r) {
            if (!val[r]) continue;
            float v = acc[tn][r] + bg
                    + esrc[(size_t)s_r[r] * HF + feat]
                    + edstA[(size_t)d_r[r] * HF + feat];
            float sg = 1.0f / (1.0f + __expf(-v));
            size_t od = (size_t)d_r[r] * HF + feat;
            atomicAdd(&ss[od], sg);
            atomicAdd(&ssh[od], sg * b2f(bh16[(size_t)s_r[r] * HF + feat]));
            // stage raw m into y; k_edge_fin finishes LN+SiLU+residual
            y[(size_t)e_r[r] * HF + feat] = v;
        }
    }
}

// ---- edge finalize: LN+SiLU+residual over staged m (round-1-proven) -----
__global__ void k_edge_fin(const float* __restrict__ ef,
                           const float* __restrict__ g_ln, const float* __restrict__ b_ln,
                           float* __restrict__ y, int E) {
    int j = threadIdx.x;   // 0..95
    int ty = threadIdx.y;  // 0..3
    int e = blockIdx.x * 4 + ty;
    bool valid = (e < E);

    float mm = 0.0f;
    size_t o = (size_t)e * HF + j;
    if (valid) mm = y[o];

    __shared__ float reds[4][HF];
    __shared__ float redq[4][HF];
    reds[ty][j] = mm;
    redq[ty][j] = mm * mm;
    __syncthreads();
    if (j < 48) { reds[ty][j] += reds[ty][j + 48]; redq[ty][j] += redq[ty][j + 48]; } __syncthreads();
    if (j < 24) { reds[ty][j] += reds[ty][j + 24]; redq[ty][j] += redq[ty][j + 24]; } __syncthreads();
    if (j < 12) { reds[ty][j] += reds[ty][j + 12]; redq[ty][j] += redq[ty][j + 12]; } __syncthreads();
    if (j < 6)  { reds[ty][j] += reds[ty][j + 6];  redq[ty][j] += redq[ty][j + 6];  } __syncthreads();
    if (j < 3)  { reds[ty][j] += reds[ty][j + 3];  redq[ty][j] += redq[ty][j + 3];  } __syncthreads();

    if (valid) {
        float sum = reds[ty][0] + reds[ty][1] + reds[ty][2];
        float sq  = redq[ty][0] + redq[ty][1] + redq[ty][2];
        float mean = sum * (1.0f / HF);
        float var  = sq * (1.0f / HF) - mean * mean;
        float lnv  = (mm - mean) * rsqrtf(var + 1e-5f) * g_ln[j] + b_ln[j];
        float silu = lnv / (1.0f + __expf(-lnv));
        y[o] = ef[o] + silu;
    }
}

// ---- node finalize: h, LN, SiLU, residual (x holds x_lin) ---------------
__global__ void k_node_fin(const float* __restrict__ nf,
                           const float* __restrict__ ssh, const float* __restrict__ ss,
                           const float* __restrict__ g_ln, const float* __restrict__ b_ln,
                           float* __restrict__ x, int n) {
    int j = threadIdx.x;
    int ty = threadIdx.y;
    int node = blockIdx.x * 4 + ty;
    bool valid = (node < n);

    float xv = 0.0f;
    if (valid) {
        size_t o = (size_t)node * HF + j;
        float h = ssh[o] / (ss[o] + 1e-6f);
        xv = x[o] + h;
    }

    __shared__ float reds[4][HF];
    __shared__ float redq[4][HF];
    reds[ty][j] = xv;
    redq[ty][j] = xv * xv;
    __syncthreads();
    if (j < 48) { reds[ty][j] += reds[ty][j + 48]; redq[ty][j] += redq[ty][j + 48]; } __syncthreads();
    if (j < 24) { reds[ty][j] += reds[ty][j + 24]; redq[ty][j] += redq[ty][j + 24]; } __syncthreads();
    if (j < 12) { reds[ty][j] += reds[ty][j + 12]; redq[ty][j] += redq[ty][j + 12]; } __syncthreads();
    if (j < 6)  { reds[ty][j] += reds[ty][j + 6];  redq[ty][j] += redq[ty][j + 6];  } __syncthreads();
    if (j < 3)  { reds[ty][j] += reds[ty][j + 3];  redq[ty][j] += redq[ty][j + 3];  } __syncthreads();

    if (valid) {
        float sum = reds[ty][0] + reds[ty][1] + reds[ty][2];
        float sq  = redq[ty][0] + redq[ty][1] + redq[ty][2];
        float mean = sum * (1.0f / HF);
        float var  = sq * (1.0f / HF) - mean * mean;
        float lnv  = (xv - mean) * rsqrtf(var + 1e-5f) * g_ln[j] + b_ln[j];
        float silu = lnv / (1.0f + __expf(-lnv));
        size_t o = (size_t)node * HF + j;
        x[o] = nf[o] + silu;
    }
}

extern "C" void kernel_launch(void* const* d_in, const int* in_sizes, int n_in,
                              void* d_out, int out_size, void* d_ws, size_t ws_size,
                              hipStream_t stream) {
    const float* node_feats = (const float*)d_in[0];
    const float* edge_feats = (const float*)d_in[1];
    const float* time_feats = (const float*)d_in[2];
    const int*   src        = (const int*)d_in[3];
    const int*   dst        = (const int*)d_in[4];
    const float* W_tp = (const float*)d_in[5];  const float* b_tp = (const float*)d_in[6];
    const float* W_sg = (const float*)d_in[7];  const float* b_sg = (const float*)d_in[8];
    const float* W_dg = (const float*)d_in[9];  const float* b_dg = (const float*)d_in[10];
    const float* W_eg = (const float*)d_in[11]; const float* b_eg = (const float*)d_in[12];
    const float* W_su = (const float*)d_in[13]; const float* b_su = (const float*)d_in[14];
    const float* W_du = (const float*)d_in[15]; const float* b_du = (const float*)d_in[16];
    const float* g_ln_e = (const float*)d_in[17]; const float* b_ln_e = (const float*)d_in[18];
    const float* g_ln_n = (const float*)d_in[19]; const float* b_ln_n = (const float*)d_in[20];

    int n = in_sizes[0] / HF;   // 100000
    int e = in_sizes[1] / HF;   // 800000

    // ws layout (floats):
    // bias4[384] | WegH(4608) | WegL(4608) | WT4H(18432) | WT4L(18432)
    // | esrc[n*96] | edstA[n*96] | ssh[n*96] | ss[n*96] | bh16 (n*96 shorts)
    float* ws    = (float*)d_ws;
    float* bias4 = ws;
    short* WegH  = (short*)(ws + 384);
    short* WegL  = (short*)(ws + 384 + 4608);
    short* WT4H  = (short*)(ws + 384 + 2 * 4608);
    short* WT4L  = (short*)(ws + 384 + 2 * 4608 + 18432);
    float* esrc  = ws + 384 + 2 * 4608 + 2 * 18432;
    float* edstA = esrc  + (size_t)n * HF;
    float* ssh   = edstA + (size_t)n * HF;
    float* ss    = ssh   + (size_t)n * HF;
    short* bh16  = (short*)(ss + (size_t)n * HF);

    float* x = (float*)d_out;            // [n, H]
    float* y = x + (size_t)n * HF;       // [e, H]

    hipMemsetAsync(ssh, 0, 2 * (size_t)n * HF * sizeof(float), stream);

    k_prep<<<HF, HF, 0, stream>>>(W_eg, W_sg, W_dg, W_du, W_su, WegH, WegL, WT4H, WT4L);
    k_bias<<<1, HF, 0, stream>>>(time_feats, W_tp, b_tp, b_sg, b_dg, b_du, b_su, bias4);

    k_node_mfma<<<(n + 63) / 64, 256, 0, stream>>>(node_feats, WT4H, WT4L, bias4,
                                                   esrc, edstA, bh16, x, n);

    k_edge_mfma<<<(e + 63) / 64, 256, 0, stream>>>(edge_feats, src, dst,
                                                   WegH, WegL, b_eg,
                                                   esrc, edstA, bh16,
                                                   ssh, ss, y, e);

    dim3 b2(HF, 4);
    k_edge_fin<<<(e + 3) / 4, b2, 0, stream>>>(edge_feats, g_ln_e, b_ln_e, y, e);

    k_node_fin<<<(n + 3) / 4, b2, 0, stream>>>(node_feats, ssh, ss,
                                               g_ln_n, b_ln_n, x, n);
}

// Round 5
// 942.642 us; speedup vs baseline: 2.2011x; 1.3590x over previous
//
#include <hip/hip_runtime.h>
#include <hip/hip_bf16.h>
#include <math.h>

#define HF 96

typedef __attribute__((ext_vector_type(8))) short bf16x8;
typedef __attribute__((ext_vector_type(4))) float f32x4;

__device__ __forceinline__ short f2b(float x) {
    __hip_bfloat16 h = __float2bfloat16(x);
    return *reinterpret_cast<short*>(&h);
}
__device__ __forceinline__ float b2f(short s) {
    __hip_bfloat16 h = *reinterpret_cast<__hip_bfloat16*>(&s);
    return __bfloat162float(h);
}

// ---- prep: transpose 5 weight matrices to bf16 hi/lo [outfeat][k] -------
__global__ void k_prep(const float* __restrict__ Weg, const float* __restrict__ Wsg,
                       const float* __restrict__ Wdg, const float* __restrict__ Wdu,
                       const float* __restrict__ Wsu,
                       short* __restrict__ WegH, short* __restrict__ WegL,
                       short* __restrict__ WT4H, short* __restrict__ WT4L) {
    int c = threadIdx.x;   // out-feature
    int k = blockIdx.x;    // input k
    if (c >= HF) return;
    const float* Ws[5] = {Weg, Wsg, Wdg, Wdu, Wsu};
#pragma unroll
    for (int w = 0; w < 5; ++w) {
        float v = Ws[w][k * HF + c];
        short hi = f2b(v);
        short lo = f2b(v - b2f(hi));
        if (w == 0) { WegH[c * HF + k] = hi; WegL[c * HF + k] = lo; }
        else {
            WT4H[((w - 1) * HF + c) * HF + k] = hi;
            WT4L[((w - 1) * HF + c) * HF + k] = lo;
        }
    }
}

// ---- bias pack: bias4[0]=b_sg+tp, [1]=b_dg, [2]=b_du, [3]=b_su ----------
__global__ void k_bias(const float* __restrict__ timef, const float* __restrict__ Wtp,
                       const float* __restrict__ btp,
                       const float* __restrict__ bsg, const float* __restrict__ bdg,
                       const float* __restrict__ bdu, const float* __restrict__ bsu,
                       float* __restrict__ bias4) {
    int j = threadIdx.x;
    if (j >= HF) return;
    float acc = btp[j];
#pragma unroll 8
    for (int k = 0; k < HF; ++k) acc = fmaf(timef[k], Wtp[k * HF + j], acc);
    bias4[0 * HF + j] = bsg[j] + acc;
    bias4[1 * HF + j] = bdg[j];
    bias4[2 * HF + j] = bdu[j];
    bias4[3 * HF + j] = bsu[j];
}

// load a row's A-fragments (hi+lo) for 3 K-tiles
__device__ __forceinline__ void load_afrag(const float* __restrict__ ap,
                                           bf16x8* ah, bf16x8* al) {
#pragma unroll
    for (int kt = 0; kt < 3; ++kt) {
        float4 f0 = *(const float4*)(ap + kt * 32);
        float4 f1 = *(const float4*)(ap + kt * 32 + 4);
        float f[8] = {f0.x, f0.y, f0.z, f0.w, f1.x, f1.y, f1.z, f1.w};
        bf16x8 h, l;
#pragma unroll
        for (int t = 0; t < 8; ++t) {
            h[t] = f2b(f[t]);
            l[t] = f2b(f[t] - b2f(h[t]));
        }
        ah[kt] = h; al[kt] = l;
    }
}

// ---- node GEMMs via split-bf16 MFMA: esrc, edstA, Bh(bf16), xlin --------
__global__ __launch_bounds__(256)
void k_node_mfma(const float* __restrict__ nf,
                 const short* __restrict__ WT4H, const short* __restrict__ WT4L,
                 const float* __restrict__ bias4,
                 float* __restrict__ esrc, float* __restrict__ edstA,
                 short* __restrict__ bh16, float* __restrict__ xlin, int n) {
    int wid = threadIdx.x >> 6;
    int lane = threadIdx.x & 63;
    int lr = lane & 15, lg = lane >> 4;
    int nbase = blockIdx.x * 64 + wid * 16;

    bf16x8 ah[3], al[3];
    {
        int arow = nbase + lr; if (arow > n - 1) arow = n - 1;
        load_afrag(nf + (size_t)arow * HF + lg * 8, ah, al);
    }

#pragma unroll
    for (int w = 0; w < 4; ++w) {
#pragma unroll
        for (int tn = 0; tn < 6; ++tn) {
            f32x4 acc = {0.f, 0.f, 0.f, 0.f};
            int feat = tn * 16 + lr;
            size_t boff = (size_t)(w * HF + feat) * HF + lg * 8;
#pragma unroll
            for (int kt = 0; kt < 3; ++kt) {
                bf16x8 bh = *(const bf16x8*)(WT4H + boff + kt * 32);
                bf16x8 bl = *(const bf16x8*)(WT4L + boff + kt * 32);
                acc = __builtin_amdgcn_mfma_f32_16x16x32_bf16(ah[kt], bh, acc, 0, 0, 0);
                acc = __builtin_amdgcn_mfma_f32_16x16x32_bf16(ah[kt], bl, acc, 0, 0, 0);
                acc = __builtin_amdgcn_mfma_f32_16x16x32_bf16(al[kt], bh, acc, 0, 0, 0);
            }
            float bias = bias4[w * HF + feat];
#pragma unroll
            for (int r = 0; r < 4; ++r) {
                int node = nbase + lg * 4 + r;
                if (node < n) {
                    float v = acc[r] + bias;
                    size_t o = (size_t)node * HF + feat;
                    if (w == 0)      esrc[o]  = v;
                    else if (w == 1) edstA[o] = v;
                    else if (w == 2) bh16[o]  = f2b(v);
                    else             xlin[o]  = v;
                }
            }
        }
    }
}

// ---- edge: gate GEMM + gathers + sigmoid + packed atomics + fused LN ----
__global__ __launch_bounds__(256)
void k_edge_mfma(const float* __restrict__ ef, const int* __restrict__ src,
                 const int* __restrict__ dst,
                 const short* __restrict__ WegH, const short* __restrict__ WegL,
                 const float* __restrict__ beg,
                 const float* __restrict__ esrc, const float* __restrict__ edstA,
                 const short* __restrict__ bh16,
                 const float* __restrict__ g_ln, const float* __restrict__ b_ln,
                 unsigned long long* __restrict__ packed,
                 float* __restrict__ y, int E) {
    int wid = threadIdx.x >> 6;
    int lane = threadIdx.x & 63;
    int lr = lane & 15, lg = lane >> 4;
    int ebase = blockIdx.x * 64 + wid * 16;

    __shared__ float redS[4][4][64];   // [wid][r][lg*16+lr]
    __shared__ float redQ[4][4][64];

    bf16x8 ah[3], al[3];
    {
        int arow = ebase + lr; if (arow > E - 1) arow = E - 1;
        load_afrag(ef + (size_t)arow * HF + lg * 8, ah, al);
    }

    f32x4 acc[6];
#pragma unroll
    for (int tn = 0; tn < 6; ++tn) {
        acc[tn] = (f32x4){0.f, 0.f, 0.f, 0.f};
        size_t boff = (size_t)(tn * 16 + lr) * HF + lg * 8;
#pragma unroll
        for (int kt = 0; kt < 3; ++kt) {
            bf16x8 bh = *(const bf16x8*)(WegH + boff + kt * 32);
            bf16x8 bl = *(const bf16x8*)(WegL + boff + kt * 32);
            acc[tn] = __builtin_amdgcn_mfma_f32_16x16x32_bf16(ah[kt], bh, acc[tn], 0, 0, 0);
            acc[tn] = __builtin_amdgcn_mfma_f32_16x16x32_bf16(ah[kt], bl, acc[tn], 0, 0, 0);
            acc[tn] = __builtin_amdgcn_mfma_f32_16x16x32_bf16(al[kt], bh, acc[tn], 0, 0, 0);
        }
    }

    int e_r[4], s_r[4], d_r[4];
    bool val[4];
#pragma unroll
    for (int r = 0; r < 4; ++r) {
        e_r[r] = ebase + lg * 4 + r;
        val[r] = (e_r[r] < E);
        int ec = val[r] ? e_r[r] : E - 1;
        s_r[r] = src[ec];
        d_r[r] = dst[ec];
    }

    // m = acc + beg + esrc[s] + edst[d]; per-lane LN partials; packed atomic
    float psum[4] = {0.f, 0.f, 0.f, 0.f}, psq[4] = {0.f, 0.f, 0.f, 0.f};
#pragma unroll
    for (int tn = 0; tn < 6; ++tn) {
        int feat = tn * 16 + lr;
        float bg = beg[feat];
#pragma unroll
        for (int r = 0; r < 4; ++r) {
            float v = acc[tn][r] + bg
                    + esrc[(size_t)s_r[r] * HF + feat]
                    + edstA[(size_t)d_r[r] * HF + feat];
            acc[tn][r] = v;
            psum[r] += v;
            psq[r]  += v * v;
            if (val[r]) {
                float sg  = 1.0f / (1.0f + __expf(-v));
                float bhv = b2f(bh16[(size_t)s_r[r] * HF + feat]);
                // fixed-point pack: lo = sg*2^24 (>=0, no carry), hi = sg*bhv*2^20
                long long lo = (long long)(unsigned)__float2int_rn(sg * 16777216.0f);
                long long hi = (long long)__float2int_rn(sg * bhv * 1048576.0f);
                unsigned long long pk = (unsigned long long)((hi << 32) + lo);
                atomicAdd(&packed[(size_t)d_r[r] * HF + feat], pk);
            }
        }
    }

    // in-wave LDS reduction of LN partials (no shfl, no barrier needed)
#pragma unroll
    for (int r = 0; r < 4; ++r) {
        redS[wid][r][lg * 16 + lr] = psum[r];
        redQ[wid][r][lg * 16 + lr] = psq[r];
    }
    float mean[4], rstd[4];
#pragma unroll
    for (int r = 0; r < 4; ++r) {
        const float4* ps4 = (const float4*)&redS[wid][r][0];
        const float4* pq4 = (const float4*)&redQ[wid][r][0];
        float s = 0.f, q = 0.f;
#pragma unroll
        for (int i = 0; i < 4; ++i) {
            float4 a = ps4[lg * 4 + i];
            float4 b = pq4[lg * 4 + i];
            s += (a.x + a.y) + (a.z + a.w);
            q += (b.x + b.y) + (b.z + b.w);
        }
        mean[r] = s * (1.0f / HF);
        float var = q * (1.0f / HF) - mean[r] * mean[r];
        rstd[r] = rsqrtf(var + 1e-5f);
    }

    // LN + SiLU + residual, final y write
#pragma unroll
    for (int tn = 0; tn < 6; ++tn) {
        int feat = tn * 16 + lr;
        float g = g_ln[feat], bb = b_ln[feat];
#pragma unroll
        for (int r = 0; r < 4; ++r) {
            if (!val[r]) continue;
            float v = acc[tn][r];
            float ln = (v - mean[r]) * rstd[r] * g + bb;
            float si = ln / (1.0f + __expf(-ln));
            size_t oe = (size_t)e_r[r] * HF + feat;
            y[oe] = ef[oe] + si;
        }
    }
}

// ---- node finalize: decode packed sums, h, LN, SiLU, residual -----------
__global__ void k_node_fin(const float* __restrict__ nf,
                           const unsigned long long* __restrict__ packed,
                           const float* __restrict__ g_ln, const float* __restrict__ b_ln,
                           float* __restrict__ x, int n) {
    int j = threadIdx.x;
    int ty = threadIdx.y;
    int node = blockIdx.x * 4 + ty;
    bool valid = (node < n);

    float xv = 0.0f;
    if (valid) {
        size_t o = (size_t)node * HF + j;
        unsigned long long t = packed[o];
        float ssv  = (float)(unsigned int)(t & 0xffffffffULL) * (1.0f / 16777216.0f);
        float sshv = (float)(int)((long long)t >> 32) * (1.0f / 1048576.0f);
        float h = sshv / (ssv + 1e-6f);
        xv = x[o] + h;
    }

    __shared__ float reds[4][HF];
    __shared__ float redq[4][HF];
    reds[ty][j] = xv;
    redq[ty][j] = xv * xv;
    __syncthreads();
    if (j < 48) { reds[ty][j] += reds[ty][j + 48]; redq[ty][j] += redq[ty][j + 48]; } __syncthreads();
    if (j < 24) { reds[ty][j] += reds[ty][j + 24]; redq[ty][j] += redq[ty][j + 24]; } __syncthreads();
    if (j < 12) { reds[ty][j] += reds[ty][j + 12]; redq[ty][j] += redq[ty][j + 12]; } __syncthreads();
    if (j < 6)  { reds[ty][j] += reds[ty][j + 6];  redq[ty][j] += redq[ty][j + 6];  } __syncthreads();
    if (j < 3)  { reds[ty][j] += reds[ty][j + 3];  redq[ty][j] += redq[ty][j + 3];  } __syncthreads();

    if (valid) {
        float sum = reds[ty][0] + reds[ty][1] + reds[ty][2];
        float sq  = redq[ty][0] + redq[ty][1] + redq[ty][2];
        float mean = sum * (1.0f / HF);
        float var  = sq * (1.0f / HF) - mean * mean;
        float lnv  = (xv - mean) * rsqrtf(var + 1e-5f) * g_ln[j] + b_ln[j];
        float silu = lnv / (1.0f + __expf(-lnv));
        size_t o = (size_t)node * HF + j;
        x[o] = nf[o] + silu;
    }
}

extern "C" void kernel_launch(void* const* d_in, const int* in_sizes, int n_in,
                              void* d_out, int out_size, void* d_ws, size_t ws_size,
                              hipStream_t stream) {
    const float* node_feats = (const float*)d_in[0];
    const float* edge_feats = (const float*)d_in[1];
    const float* time_feats = (const float*)d_in[2];
    const int*   src        = (const int*)d_in[3];
    const int*   dst        = (const int*)d_in[4];
    const float* W_tp = (const float*)d_in[5];  const float* b_tp = (const float*)d_in[6];
    const float* W_sg = (const float*)d_in[7];  const float* b_sg = (const float*)d_in[8];
    const float* W_dg = (const float*)d_in[9];  const float* b_dg = (const float*)d_in[10];
    const float* W_eg = (const float*)d_in[11]; const float* b_eg = (const float*)d_in[12];
    const float* W_su = (const float*)d_in[13]; const float* b_su = (const float*)d_in[14];
    const float* W_du = (const float*)d_in[15]; const float* b_du = (const float*)d_in[16];
    const float* g_ln_e = (const float*)d_in[17]; const float* b_ln_e = (const float*)d_in[18];
    const float* g_ln_n = (const float*)d_in[19]; const float* b_ln_n = (const float*)d_in[20];

    int n = in_sizes[0] / HF;   // 100000
    int e = in_sizes[1] / HF;   // 800000

    // ws layout (floats):
    // bias4[384] | WegH(4608) | WegL(4608) | WT4H(18432) | WT4L(18432)
    // | esrc[n*96] | edstA[n*96] | packed u64 [n*96] | bh16 (n*96 shorts)
    float* ws    = (float*)d_ws;
    float* bias4 = ws;
    short* WegH  = (short*)(ws + 384);
    short* WegL  = (short*)(ws + 384 + 4608);
    short* WT4H  = (short*)(ws + 384 + 2 * 4608);
    short* WT4L  = (short*)(ws + 384 + 2 * 4608 + 18432);
    float* esrc  = ws + 384 + 2 * 4608 + 2 * 18432;
    float* edstA = esrc  + (size_t)n * HF;
    unsigned long long* packed = (unsigned long long*)(edstA + (size_t)n * HF);
    short* bh16  = (short*)(packed + (size_t)n * HF);

    float* x = (float*)d_out;            // [n, H]
    float* y = x + (size_t)n * HF;       // [e, H]

    hipMemsetAsync(packed, 0, (size_t)n * HF * sizeof(unsigned long long), stream);

    k_prep<<<HF, HF, 0, stream>>>(W_eg, W_sg, W_dg, W_du, W_su, WegH, WegL, WT4H, WT4L);
    k_bias<<<1, HF, 0, stream>>>(time_feats, W_tp, b_tp, b_sg, b_dg, b_du, b_su, bias4);

    k_node_mfma<<<(n + 63) / 64, 256, 0, stream>>>(node_feats, WT4H, WT4L, bias4,
                                                   esrc, edstA, bh16, x, n);

    k_edge_mfma<<<(e + 63) / 64, 256, 0, stream>>>(edge_feats, src, dst,
                                                   WegH, WegL, b_eg,
                                                   esrc, edstA, bh16,
                                                   g_ln_e, b_ln_e,
                                                   packed, y, e);

    dim3 b2(HF, 4);
    k_node_fin<<<(n + 3) / 4, b2, 0, stream>>>(node_feats, packed,
                                               g_ln_n, b_ln_n, x, n);
}